// Round 11
// baseline (37.626 us; speedup 1.0000x reference)
//
#include <hip/hip_runtime.h>

#define H 1024
#define W 1024
#define TILE 32
#define SR 40    // hsum rows: TILE + 8 (halo4)
#define SC 36    // hsum cols: TILE + 4
#define VR 36    // vw rows:   TILE + 4
#define VC 36    // vw cols:   TILE + 4

// s_vw layout: flat with a 16B bubble every 2 rows to spread row base across
// 8 bank groups (stride 576B ≡ 16 banks caused 4-way write conflicts).
// idx(row,col) = row*36 + (row>>1) + col  — within-row contiguous, and since
// pr0 is even, (pr0+r)>>1 = pr0/2 + (r>>1) folds to compile-time immediates.
#define VWI(row, col) ((row) * VC + ((row) >> 1) + (col))
#define VWSZ (VR * VC + (VR / 2) + 2)   // 1316 float4s

// LDS: s_su 40*36*8 = 11520 B + s_vw 1316*16 = 21056 B -> 32576 B -> 5 blocks/CU.

__global__ __launch_bounds__(256)
void kuwahara_kernel(const float* __restrict__ inp, float* __restrict__ out) {
    __shared__ float2 s_su[SR][SC];   // (hsum luma, hsum luma^2), halo4 rows
    __shared__ float4 s_vw[VWSZ];     // (r, g, b, k->weight), bubble-padded

    const int tid = threadIdx.x;

    // ---- XCD-aware swizzle: each XCD owns 512 contiguous tiles (x-fastest) ----
    unsigned wg  = blockIdx.x;          // grid = 4096 linear blocks
    unsigned lin = (wg & 7u) * 512u + (wg >> 3);
    const int n  = lin >> 10;
    const int y0 = ((lin >> 5) & 31) * TILE;
    const int x0 = (lin & 31) * TILE;

    const float* __restrict__ pR = inp + ((size_t)(4*n + 0) << 20);
    const float* __restrict__ pG = inp + ((size_t)(4*n + 1) << 20);
    const float* __restrict__ pB = inp + ((size_t)(4*n + 2) << 20);
    const float* __restrict__ pK = inp + ((size_t)(4*n + 3) << 20);

    const int tx  = tid & 31;   // column within tile
    const int tg  = tid >> 5;   // row-group: owns rows 4*tg .. 4*tg+3
    const int gx  = x0 + tx;
    const int pr0 = tg << 2;    // even -> VWI folds to immediates in stage 4

    // ---- k at this thread's 4 output pixels (fp32 exact; L1/L2-resident) ----
    float kc[4];
#pragma unroll
    for (int p = 0; p < 4; ++p)
        kc[p] = pK[((y0 + pr0 + p) << 10) + gx];

    // ---- stage 1 (fully fused, SINGLE load of rgbk per halo pixel):
    // luma + horizontal 5-sums via __shfl_down, AND s_vw fill from the same
    // registers. 10 lanes/row (one 4-px quad each); 6 rows/wave; 2 passes.
    {
        const int lane = tid & 63;
        const int wid  = tid >> 6;
        const int rloc = lane / 10;            // 0..5 active, 6 idle
        const int qq   = lane - rloc * 10;     // quad index 0..9
        const int gcs  = x0 - 4 + (qq << 2);
#pragma unroll
        for (int pass = 0; pass < 2; ++pass) {
            int row = pass * 24 + wid * 6 + rloc;
            bool act = (rloc < 6) && (row < SR);
            bool vwrow = act && (row >= 2) && (row < SR - 2);
            float l0 = 0.f, l1 = 0.f, l2 = 0.f, l3 = 0.f;
            float rr[4], gg[4], bb[4], kk[4];
            if (act) {
                int gy = y0 - 4 + row;
                int cy = min(max(gy, 0), H - 1);
                const int base = cy << 10;
                if (gcs >= 0 && gcs <= W - 4) {         // x-interior: vector
                    float4 r4 = *(const float4*)(pR + base + gcs);
                    float4 g4 = *(const float4*)(pG + base + gcs);
                    float4 b4 = *(const float4*)(pB + base + gcs);
                    rr[0]=r4.x; rr[1]=r4.y; rr[2]=r4.z; rr[3]=r4.w;
                    gg[0]=g4.x; gg[1]=g4.y; gg[2]=g4.z; gg[3]=g4.w;
                    bb[0]=b4.x; bb[1]=b4.y; bb[2]=b4.z; bb[3]=b4.w;
                    if (vwrow) {
                        float4 k4 = *(const float4*)(pK + base + gcs);
                        kk[0]=k4.x; kk[1]=k4.y; kk[2]=k4.z; kk[3]=k4.w;
                    }
                } else {                                 // x-border: clamped
#pragma unroll
                    for (int e = 0; e < 4; ++e) {
                        int cx = min(max(gcs + e, 0), W - 1);
                        rr[e] = pR[base + cx]; gg[e] = pG[base + cx];
                        bb[e] = pB[base + cx];
                        kk[e] = vwrow ? pK[base + cx] : 0.f;
                    }
                }
                bool rowIn = ((unsigned)gy < (unsigned)H);
                float lv[4];
#pragma unroll
                for (int e = 0; e < 4; ++e) {
                    bool colIn = ((unsigned)(gcs + e) < (unsigned)W);
                    lv[e] = (rowIn && colIn)
                        ? fmaf(0.2126f, rr[e], fmaf(0.7152f, gg[e], 0.0722f * bb[e]))
                        : 0.0f;                          // zero pad rows AND cols
                }
                l0 = lv[0]; l1 = lv[1]; l2 = lv[2]; l3 = lv[3];
            }
            // neighbor quad's luma (same row: qq<=8 pulls from qq+1)
            float l4 = __shfl_down(l0, 1, 64);
            float l5 = __shfl_down(l1, 1, 64);
            float l6 = __shfl_down(l2, 1, 64);
            float l7 = __shfl_down(l3, 1, 64);
            if (act && qq < 9) {
                float s0 = ((l0 + l1) + (l2 + l3)) + l4;
                float s1 = s0 - l0 + l5;
                float s2 = s1 - l1 + l6;
                float s3 = s2 - l2 + l7;
                float m0=l0*l0, m1=l1*l1, m2=l2*l2, m3=l3*l3;
                float m4=l4*l4, m5=l5*l5, m6=l6*l6, m7=l7*l7;
                float u0 = ((m0 + m1) + (m2 + m3)) + m4;
                float u1 = u0 - m0 + m5;
                float u2 = u1 - m1 + m6;
                float u3 = u2 - m2 + m7;
                int c = qq << 2;
                *(float4*)&s_su[row][c]     = make_float4(s0, u0, s1, u1);
                *(float4*)&s_su[row][c + 2] = make_float4(s2, u2, s3, u3);
            }
            if (vwrow) {                                 // s_vw from SAME regs
#pragma unroll
                for (int e = 0; e < 4; ++e) {
                    int iv = (qq << 2) + e - 2;
                    if ((unsigned)iv < (unsigned)VC)
                        s_vw[VWI(row - 2, iv)] = make_float4(rr[e], gg[e], bb[e], kk[e]);
                }
            }
        }
    }
    __syncthreads();

    // ---- stage 3: vertical 5-sum -> variance -> weight. 2-wide tasks ----
    // 648 tasks: j2 in [0,36), q in [0,18); contiguous 256B reads per row.
    for (int idx = tid; idx < VR * 18; idx += 256) {
        int j2 = idx / 18, q = idx - j2 * 18;
        int c  = q << 1;
        int gyc = min(max(y0 - 2 + j2, 0), H - 1);  // clamped window center row
        int js  = gyc - y0 + 2;
        int g0  = x0 - 2 + c;                       // unclamped center col (e=0)
        float s_a, u_a, s_b, u_b;
        if (g0 >= 0 && g0 + 1 <= W - 1) {           // both cols interior
            float4 acc = make_float4(0.f, 0.f, 0.f, 0.f);
#pragma unroll
            for (int r = 0; r < 5; ++r) {
                float4 v = *(const float4*)&s_su[js + r][c];
                acc.x += v.x; acc.y += v.y; acc.z += v.z; acc.w += v.w;
            }
            s_a = acc.x; u_a = acc.y; s_b = acc.z; u_b = acc.w;
        } else {                                    // x-border: clamped scalar
            float sv[2], uv[2];
#pragma unroll
            for (int e = 0; e < 2; ++e) {
                int is = min(max(g0 + e, 0), W - 1) - x0 + 2;
                float ss = 0.f, sq = 0.f;
#pragma unroll
                for (int r = 0; r < 5; ++r) {
                    float2 v = s_su[js + r][is];
                    ss += v.x; sq += v.y;
                }
                sv[e] = ss; uv[e] = sq;
            }
            s_a = sv[0]; u_a = uv[0]; s_b = sv[1]; u_b = uv[1];
        }
        {
            float mean = s_a * 0.04f, msq = u_a * 0.04f;
            float var  = fabsf(msq - mean * mean);
            float kv   = s_vw[VWI(j2, c)].w;
            s_vw[VWI(j2, c)].w = __expf(-var * 64.0f * kv);
        }
        {
            float mean = s_b * 0.04f, msq = u_b * 0.04f;
            float var  = fabsf(msq - mean * mean);
            float kv   = s_vw[VWI(j2, c + 1)].w;
            s_vw[VWI(j2, c + 1)].w = __expf(-var * 64.0f * kv);
        }
    }
    __syncthreads();

    // ---- spatial-falloff constants (late, short live ranges) ----
    float t1[4], t4[4];
#pragma unroll
    for (int p = 0; p < 4; ++p) {
        float t = __expf(-2.56f * (1.0f - kc[p]));   // t^(dx^2+dy^2) base
        t1[p] = t;
        t4[p] = (t * t) * (t * t);
    }

    // ---- stage 4: 25-tap filter; factorized row sums shared across 4 px ----
    float accR[4], accG[4], accB[4], accW[4];
#pragma unroll
    for (int p = 0; p < 4; ++p) { accR[p] = accG[p] = accB[p] = accW[p] = 0.f; }

#pragma unroll
    for (int r = 0; r < 8; ++r) {
        const float4* row = &s_vw[VWI(pr0 + r, tx)]; // single base, imm offsets
        float4 a0 = row[0], a1 = row[1], a2 = row[2], a3 = row[3], a4 = row[4];
        // partial sums by |dx|: S0 (dx=0), S1 (|dx|=1), S2 (|dx|=2)
        float S0w = a2.w;
        float S0x = a2.w * a2.x, S0y = a2.w * a2.y, S0z = a2.w * a2.z;
        float S1w = a1.w + a3.w;
        float S1x = a1.w * a1.x + a3.w * a3.x;
        float S1y = a1.w * a1.y + a3.w * a3.y;
        float S1z = a1.w * a1.z + a3.w * a3.z;
        float S2w = a0.w + a4.w;
        float S2x = a0.w * a0.x + a4.w * a4.x;
        float S2y = a0.w * a0.y + a4.w * a4.y;
        float S2z = a0.w * a0.z + a4.w * a4.z;
#pragma unroll
        for (int p = 0; p < 4; ++p) {
            const int dy = r - 2 - p;                // compile-time after unroll
            if (dy < -2 || dy > 2) continue;
            const int ady = dy < 0 ? -dy : dy;
            float rw = S0w + t1[p] * S1w + t4[p] * S2w;
            float rx = S0x + t1[p] * S1x + t4[p] * S2x;
            float ry = S0y + t1[p] * S1y + t4[p] * S2y;
            float rz = S0z + t1[p] * S1z + t4[p] * S2z;
            if (ady == 0) {
                accR[p] += rx; accG[p] += ry; accB[p] += rz; accW[p] += rw;
            } else {
                float rf = (ady == 1) ? t1[p] : t4[p];
                accR[p] += rf * rx; accG[p] += rf * ry;
                accB[p] += rf * rz; accW[p] += rf * rw;
            }
        }
    }

    float* __restrict__ oR = out + ((size_t)(3*n + 0) << 20);
    float* __restrict__ oG = out + ((size_t)(3*n + 1) << 20);
    float* __restrict__ oB = out + ((size_t)(3*n + 2) << 20);
#pragma unroll
    for (int p = 0; p < 4; ++p) {
        float4 cen = s_vw[VWI(pr0 + p + 2, tx + 2)]; // center rgb from LDS
        float cb = 16.0f + kc[p] * (0.001f - 16.0f); // center boost
        accR[p] += cb * cen.x;
        accG[p] += cb * cen.y;
        accB[p] += cb * cen.z;
        accW[p] += cb;
        float inv = __builtin_amdgcn_rcpf(accW[p]);
        int off = ((y0 + pr0 + p) << 10) + gx;
        oR[off] = cen.x + kc[p] * (accR[p] * inv - cen.x);
        oG[off] = cen.y + kc[p] * (accG[p] * inv - cen.y);
        oB[off] = cen.z + kc[p] * (accB[p] * inv - cen.z);
    }
}

extern "C" void kernel_launch(void* const* d_in, const int* in_sizes, int n_in,
                              void* d_out, int out_size, void* d_ws, size_t ws_size,
                              hipStream_t stream) {
    const float* inp = (const float*)d_in[0];
    float* out = (float*)d_out;
    hipLaunchKernelGGL(kuwahara_kernel, dim3(4096), dim3(256), 0, stream, inp, out);
}